// Round 4
// baseline (80.681 us; speedup 1.0000x reference)
//
#include <hip/hip_runtime.h>

#define NELEM 21600
#define KSEL 1000
#define MAXB 18
#define NT 1024
#define CAP 2048
#define NQ (NELEM * 6 / 4)     // 32400 float4s per sample
#define NQF (NQ / NT)          // 31 full iterations
#define NQT (NQ - NQF * NT)    // 656 tail

typedef unsigned long long ull;

// monotone map: ascending uint key <-> ascending float
__device__ __forceinline__ unsigned fkey(float f) {
  unsigned u = __float_as_uint(f);
  return (u & 0x80000000u) ? ~u : (u | 0x80000000u);
}

// Wave-shuffle bucket select over hist[2048]. 16 waves x 128 buckets.
// Picks bucket B with cntGe(B) >= target > cntGe(B+1).
__device__ void select_bucket(const unsigned* hist, unsigned target,
                              volatile unsigned* chunkSuf,  // [16] scratch
                              unsigned* outB, unsigned* outCnt, unsigned* outAbove) {
  const int tid = threadIdx.x;
  const int w = tid >> 6, l = tid & 63;
  unsigned h1 = hist[w * 128 + 2 * l + 1];
  unsigned s = hist[w * 128 + 2 * l] + h1;
  #pragma unroll
  for (int d = 1; d < 64; d <<= 1) {
    unsigned t = __shfl_down(s, d);
    if (l + d < 64) s += t;
  }
  if (l == 0) chunkSuf[w] = s;
  __syncthreads();
  if (w == 0) {
    unsigned ct = (l < 16) ? chunkSuf[l] : 0u;
    unsigned cs = ct;
    #pragma unroll
    for (int d = 1; d < 16; d <<= 1) {
      unsigned t = __shfl_down(cs, d);
      if (l + d < 16) cs += t;
    }
    if (l < 16) chunkSuf[l] = cs - ct;   // count in chunks strictly after l
  }
  __syncthreads();
  unsigned base = chunkSuf[w];
  unsigned sufE = s + base;
  unsigned sN = __shfl_down(s, 1);
  unsigned sufN = ((l < 63) ? sN : 0u) + base;
  unsigned geOdd = sufN + h1;
  if (sufE >= target && geOdd < target) { *outB = w * 128u + 2u * l;     *outCnt = sufE;  *outAbove = geOdd; }
  if (geOdd >= target && sufN < target) { *outB = w * 128u + 2u * l + 1; *outCnt = geOdd; *outAbove = sufN;  }
  __syncthreads();
}

__global__ __launch_bounds__(NT) void rpn_kernel(
    const float* __restrict__ x, const float* __restrict__ anch,
    float* __restrict__ out) {
  const int b = blockIdx.x;
  const int tid = threadIdx.x;
  const float* xb = x + (size_t)b * NELEM * 6;
  const float4* xq = (const float4*)xb;

  __shared__ unsigned hist[2048];
  __shared__ unsigned chunkSuf[16];
  __shared__ ull selPk[CAP];
  __shared__ float bX1[KSEL], bY1[KSEL], bX2[KSEL], bY2[KSEL], bAr[KSEL];
  __shared__ unsigned sB, sCnt, sAbove;
  __shared__ unsigned baseKey;
  __shared__ unsigned cnt;
  __shared__ int keptRank[MAXB];
  __shared__ int numKept;

  hist[2 * tid] = 0u; hist[2 * tid + 1] = 0u;
  __syncthreads();

  // ---- scan 1: coalesced float4 read, histogram top 11 key bits ----
  #pragma unroll 4
  for (int k = 0; k < NQF; ++k) {
    int g = tid + (k << 10);
    float4 v = xq[g];
    int r = g % 3;                       // g%3==0 -> score v.x; ==1 -> v.z; ==2 -> none
    if (r == 0)      atomicAdd(&hist[fkey(v.x) >> 21], 1u);
    else if (r == 1) atomicAdd(&hist[fkey(v.z) >> 21], 1u);
  }
  if (tid < NQT) {
    int g = tid + (NQF << 10);
    float4 v = xq[g];
    int r = g % 3;
    if (r == 0)      atomicAdd(&hist[fkey(v.x) >> 21], 1u);
    else if (r == 1) atomicAdd(&hist[fkey(v.z) >> 21], 1u);
  }
  __syncthreads();
  select_bucket(hist, KSEL, chunkSuf, &sB, &sCnt, &sAbove);
  const unsigned b1 = sB, cnt1 = sCnt, above1 = sAbove;

  if (cnt1 <= CAP) {
    if (tid == 0) { baseKey = b1 << 21; cnt = 0u; }
  } else {
    // rare fat-bucket: refine within bucket b1 on next 11 bits
    hist[2 * tid] = 0u; hist[2 * tid + 1] = 0u;
    __syncthreads();
    #pragma unroll 4
    for (int k = 0; k < NQF; ++k) {
      int g = tid + (k << 10);
      float4 v = xq[g];
      int r = g % 3;
      if (r != 2) {
        unsigned kk = fkey(r == 0 ? v.x : v.z);
        if ((kk >> 21) == b1) atomicAdd(&hist[(kk >> 10) & 0x7FFu], 1u);
      }
    }
    if (tid < NQT) {
      int g = tid + (NQF << 10);
      float4 v = xq[g];
      int r = g % 3;
      if (r != 2) {
        unsigned kk = fkey(r == 0 ? v.x : v.z);
        if ((kk >> 21) == b1) atomicAdd(&hist[(kk >> 10) & 0x7FFu], 1u);
      }
    }
    __syncthreads();
    select_bucket(hist, KSEL - above1, chunkSuf, &sB, &sCnt, &sAbove);
    if (tid == 0) { baseKey = (b1 << 21) | (sB << 10); cnt = 0u; }
  }
  __syncthreads();

  // ---- compact: coalesced re-scan (L2-hot), push packed (key, ~idx) ----
  const unsigned TB = baseKey;
  #pragma unroll 4
  for (int k = 0; k < NQF; ++k) {
    int g = tid + (k << 10);
    float4 v = xq[g];
    int r = g % 3;
    if (r != 2) {
      unsigned kk = fkey(r == 0 ? v.x : v.z);
      if (kk >= TB) {
        unsigned p = atomicAdd(&cnt, 1u);
        unsigned idx = 2u * (unsigned)(g / 3) + (r == 1 ? 1u : 0u);
        if (p < CAP) selPk[p] = ((ull)kk << 32) | (unsigned)(~idx);
      }
    }
  }
  if (tid < NQT) {
    int g = tid + (NQF << 10);
    float4 v = xq[g];
    int r = g % 3;
    if (r != 2) {
      unsigned kk = fkey(r == 0 ? v.x : v.z);
      if (kk >= TB) {
        unsigned p = atomicAdd(&cnt, 1u);
        unsigned idx = 2u * (unsigned)(g / 3) + (r == 1 ? 1u : 0u);
        if (p < CAP) selPk[p] = ((ull)kk << 32) | (unsigned)(~idx);
      }
    }
  }
  __syncthreads();
  const unsigned realCnt = (cnt < CAP) ? cnt : CAP;
  for (unsigned i = realCnt + tid; i < CAP; i += NT) selPk[i] = 0ull;
  __syncthreads();

  // ---- hybrid bitonic sort 2048 descending ----
  {
    const int w = tid >> 6, L = tid & 63;
    const int ea = (w << 7) | (L << 1);       // element index of reg a; reg b = ea+1
    // session 1: stages k=2..128 fully in registers (wave-local window of 128)
    ull a = selPk[ea], bb = selPk[ea + 1];
    #pragma unroll
    for (unsigned k = 2; k <= 128; k <<= 1) {
      #pragma unroll
      for (unsigned j = k >> 1; j >= 2; j >>= 1) {
        bool up = ((ea & k) == 0);
        bool lower = ((ea & j) == 0);
        bool takeMax = (up == lower);
        ull oa = __shfl_xor(a, (int)(j >> 1));
        ull ob = __shfl_xor(bb, (int)(j >> 1));
        a  = takeMax ? (a  > oa ? a  : oa) : (a  < oa ? a  : oa);
        bb = takeMax ? (bb > ob ? bb : ob) : (bb < ob ? bb : ob);
      }
      bool up = ((ea & k) == 0);
      ull mx = a > bb ? a : bb, mn = a > bb ? bb : a;
      a = up ? mx : mn; bb = up ? mn : mx;
    }
    selPk[ea] = a; selPk[ea + 1] = bb;
    __syncthreads();
    // stages k=256..2048: LDS exchange for j>=128, register finish for j<=64
    for (unsigned k = 256; k <= 2048; k <<= 1) {
      for (unsigned j = k >> 1; j >= 128; j >>= 1) {
        unsigned p = (unsigned)tid;
        unsigned vi = ((p & ~(j - 1)) << 1) | (p & (j - 1));
        unsigned li = vi | j;
        ull av = selPk[vi], cv = selPk[li];
        bool doswap = ((vi & k) == 0) ? (av < cv) : (av > cv);
        if (doswap) { selPk[vi] = cv; selPk[li] = av; }
        __syncthreads();
      }
      a = selPk[ea]; bb = selPk[ea + 1];
      bool up = (((unsigned)(w << 7) & k) == 0);   // wave-uniform for k>=256
      #pragma unroll
      for (unsigned j = 64; j >= 2; j >>= 1) {
        bool lower = ((ea & j) == 0);
        bool takeMax = (up == lower);
        ull oa = __shfl_xor(a, (int)(j >> 1));
        ull ob = __shfl_xor(bb, (int)(j >> 1));
        a  = takeMax ? (a  > oa ? a  : oa) : (a  < oa ? a  : oa);
        bb = takeMax ? (bb > ob ? bb : ob) : (bb < ob ? bb : ob);
      }
      ull mx = a > bb ? a : bb, mn = a > bb ? bb : a;
      a = up ? mx : mn; bb = up ? mn : mx;
      selPk[ea] = a; selPk[ea + 1] = bb;
      __syncthreads();
    }
  }

  // ---- decode first 1000 into box arrays for NMS ----
  if (tid < KSEL) {
    unsigned idx = ~(unsigned)selPk[tid];
    const float* e = xb + (size_t)idx * 6;
    float r0 = e[2], r1 = e[3], r2 = e[4], r3 = e[5];
    unsigned pp = (idx / 9u) % 60u;
    unsigned qq = idx / 540u;
    unsigned sr = idx % 9u;
    const float* ap = anch + (((pp * 40u + qq) * 9u + sr) * 4u);
    float ax = ap[0], ay = ap[1], aw = ap[2], ah = ap[3];
    float xc = r0 * aw + ax;
    float yc = r1 * ah + ay;
    float w = aw * expf(r2);
    float h = ah * expf(r3);
    float x1 = xc - 0.5f * w, x2 = xc + 0.5f * w;
    float y1 = yc - 0.5f * h, y2 = yc + 0.5f * h;
    bX1[tid] = x1; bY1[tid] = y1; bX2[tid] = x2; bY2[tid] = y2;
    bAr[tid] = (x2 - x1) * (y2 - y1);
  }
  __syncthreads();

  // ---- greedy NMS on wave 0, early exit at 18 kept ----
  if (tid < 64) {
    const int lane = tid;
    int nk = 0;
    float kx1 = 0.f, ky1 = 0.f, kx2 = 0.f, ky2 = 0.f;  // lane i holds kept box i
    int krank = -1;
    for (int base = 0; base < KSEL && nk < MAXB; base += 64) {
      int c = base + lane;
      bool alive = (c < KSEL);
      int cc = alive ? c : 0;
      float x1 = bX1[cc], y1 = bY1[cc], x2 = bX2[cc], y2 = bY2[cc], ar = bAr[cc];
      for (int i = 0; i < nk; ++i) {
        float px1 = __shfl(kx1, i), py1 = __shfl(ky1, i);
        float px2 = __shfl(kx2, i), py2 = __shfl(ky2, i);
        float iw = fmaxf(fminf(x2, px2) - fmaxf(x1, px1), 0.f);
        float ih = fmaxf(fminf(y2, py2) - fmaxf(y1, py1), 0.f);
        if (iw * ih / ar > 0.5f) alive = false;
      }
      unsigned long long m = __ballot(alive);
      while (m) {
        int i = __builtin_ctzll(m);      // lowest alive lane = best remaining score
        float px1 = __shfl(x1, i), py1 = __shfl(y1, i);
        float px2 = __shfl(x2, i), py2 = __shfl(y2, i);
        if (lane == nk) { kx1 = px1; ky1 = py1; kx2 = px2; ky2 = py2; krank = base + i; }
        ++nk;
        if (nk >= MAXB) break;
        if (alive && lane != i) {
          float iw = fmaxf(fminf(x2, px2) - fmaxf(x1, px1), 0.f);
          float ih = fmaxf(fminf(y2, py2) - fmaxf(y1, py1), 0.f);
          if (iw * ih / ar > 0.5f) alive = false;
        }
        if (lane == i) alive = false;
        m = __ballot(alive);
      }
    }
    if (lane == 0) numKept = nk;
    if (lane < nk) keptRank[lane] = krank;
  }
  __syncthreads();

  // ---- output: kept rows then pad rows cand[j - n]; re-decode ----
  const int n = numKept;
  if (tid < MAXB) {
    int j = tid;
    int r = (j < n) ? keptRank[j] : (j - n);
    unsigned idx = ~(unsigned)selPk[r];
    const float* e = xb + (size_t)idx * 6;
    float sc = e[0];
    float r0 = e[2], r1 = e[3], r2 = e[4], r3 = e[5];
    unsigned pp = (idx / 9u) % 60u;
    unsigned qq = idx / 540u;
    unsigned sr = idx % 9u;
    const float* ap = anch + (((pp * 40u + qq) * 9u + sr) * 4u);
    float ax = ap[0], ay = ap[1], aw = ap[2], ah = ap[3];
    float xc = r0 * aw + ax;
    float yc = r1 * ah + ay;
    float w = aw * expf(r2);
    float h = ah * expf(r3);
    float* o = out + b * (MAXB * 5) + j * 5;
    o[0] = xc; o[1] = yc; o[2] = w; o[3] = h; o[4] = sc;
  }
}

extern "C" void kernel_launch(void* const* d_in, const int* in_sizes, int n_in,
                              void* d_out, int out_size, void* d_ws, size_t ws_size,
                              hipStream_t stream) {
  const float* x = (const float*)d_in[0];
  const float* anch = (const float*)d_in[1];
  float* out = (float*)d_out;
  const int B = in_sizes[0] / (NELEM * 6);
  rpn_kernel<<<dim3(B), dim3(NT), 0, stream>>>(x, anch, out);
}

// Round 5
// 63.936 us; speedup vs baseline: 1.2619x; 1.2619x over previous
//
#include <hip/hip_runtime.h>

#define NELEM 21600
#define KSEL 1000
#define MAXB 18
#define NT 1024
#define CAP 2048
#define NFULL 21                    // 21*1024 = 21504
#define NTAIL (NELEM - NFULL * NT)  // 96

typedef unsigned long long ull;

// monotone map: ascending uint key <-> ascending float
__device__ __forceinline__ unsigned fkey(float f) {
  unsigned u = __float_as_uint(f);
  return (u & 0x80000000u) ? ~u : (u | 0x80000000u);
}
__device__ __forceinline__ float unfkey(unsigned k) {
  unsigned u = (k & 0x80000000u) ? (k ^ 0x80000000u) : ~k;
  return __uint_as_float(u);
}

// Wave-shuffle bucket select over hist[2048]. 16 waves x 128 buckets.
// Picks bucket B with cntGe(B) >= target > cntGe(B+1).
__device__ void select_bucket(const unsigned* hist, unsigned target,
                              volatile unsigned* chunkSuf,  // [16] scratch
                              unsigned* outB, unsigned* outCnt, unsigned* outAbove) {
  const int tid = threadIdx.x;
  const int w = tid >> 6, l = tid & 63;
  unsigned h1 = hist[w * 128 + 2 * l + 1];
  unsigned s = hist[w * 128 + 2 * l] + h1;
  #pragma unroll
  for (int d = 1; d < 64; d <<= 1) {
    unsigned t = __shfl_down(s, d);
    if (l + d < 64) s += t;
  }
  if (l == 0) chunkSuf[w] = s;
  __syncthreads();
  if (w == 0) {
    unsigned ct = (l < 16) ? chunkSuf[l] : 0u;
    unsigned cs = ct;
    #pragma unroll
    for (int d = 1; d < 16; d <<= 1) {
      unsigned t = __shfl_down(cs, d);
      if (l + d < 16) cs += t;
    }
    if (l < 16) chunkSuf[l] = cs - ct;   // count in chunks strictly after l
  }
  __syncthreads();
  unsigned base = chunkSuf[w];
  unsigned sufE = s + base;
  unsigned sN = __shfl_down(s, 1);
  unsigned sufN = ((l < 63) ? sN : 0u) + base;
  unsigned geOdd = sufN + h1;
  if (sufE >= target && geOdd < target) { *outB = w * 128u + 2u * l;     *outCnt = sufE;  *outAbove = geOdd; }
  if (geOdd >= target && sufN < target) { *outB = w * 128u + 2u * l + 1; *outCnt = geOdd; *outAbove = sufN;  }
  __syncthreads();
}

__global__ __launch_bounds__(NT, 4) void rpn_kernel(
    const float* __restrict__ x, const float* __restrict__ anch,
    float* __restrict__ out) {
  const int b = blockIdx.x;
  const int tid = threadIdx.x;
  const float* xb = x + (size_t)b * NELEM * 6;

  __shared__ unsigned hist[2048];
  __shared__ unsigned chunkSuf[16];
  __shared__ ull selPk[CAP];
  __shared__ float bX1[KSEL], bY1[KSEL], bX2[KSEL], bY2[KSEL], bAr[KSEL];
  __shared__ unsigned sB, sCnt, sAbove;
  __shared__ unsigned baseKey;
  __shared__ unsigned cnt;
  __shared__ int keptRank[MAXB];
  __shared__ int numKept;

  hist[2 * tid] = 0u; hist[2 * tid + 1] = 0u;

  // ---- deep prefetch of this thread's 21 scores; pin them live in VGPRs ----
  float sv[NFULL];
  #pragma unroll
  for (int u = 0; u < NFULL; ++u)
    sv[u] = xb[(size_t)(tid + (u << 10)) * 6];
  float stail = 0.f;
  const bool hastail = tid < NTAIL;
  if (hastail) stail = xb[(size_t)(tid + NFULL * NT) * 6];
  // Force ALL loads to be issued and completed here (single vmcnt drain):
  asm volatile("" :
      "+v"(sv[0]), "+v"(sv[1]), "+v"(sv[2]), "+v"(sv[3]), "+v"(sv[4]),
      "+v"(sv[5]), "+v"(sv[6]), "+v"(sv[7]), "+v"(sv[8]), "+v"(sv[9]),
      "+v"(sv[10]), "+v"(sv[11]), "+v"(sv[12]), "+v"(sv[13]), "+v"(sv[14]),
      "+v"(sv[15]), "+v"(sv[16]), "+v"(sv[17]), "+v"(sv[18]), "+v"(sv[19]),
      "+v"(sv[20]), "+v"(stail));
  __syncthreads();

  // ---- histogram of top 11 key bits (from registers) ----
  #pragma unroll
  for (int u = 0; u < NFULL; ++u)
    atomicAdd(&hist[fkey(sv[u]) >> 21], 1u);
  if (hastail) atomicAdd(&hist[fkey(stail) >> 21], 1u);
  __syncthreads();
  select_bucket(hist, KSEL, chunkSuf, &sB, &sCnt, &sAbove);
  const unsigned b1 = sB, cnt1 = sCnt, above1 = sAbove;

  if (cnt1 <= CAP) {
    if (tid == 0) { baseKey = b1 << 21; cnt = 0u; }
  } else {
    // rare fat-bucket: refine within bucket b1 on next 11 bits (registers again)
    hist[2 * tid] = 0u; hist[2 * tid + 1] = 0u;
    __syncthreads();
    #pragma unroll
    for (int u = 0; u < NFULL; ++u) {
      unsigned k = fkey(sv[u]);
      if ((k >> 21) == b1) atomicAdd(&hist[(k >> 10) & 0x7FFu], 1u);
    }
    if (hastail) {
      unsigned k = fkey(stail);
      if ((k >> 21) == b1) atomicAdd(&hist[(k >> 10) & 0x7FFu], 1u);
    }
    __syncthreads();
    select_bucket(hist, KSEL - above1, chunkSuf, &sB, &sCnt, &sAbove);
    if (tid == 0) { baseKey = (b1 << 21) | (sB << 10); cnt = 0u; }
  }
  __syncthreads();

  // ---- compact from registers: keys >= baseKey, packed (key, ~idx) ----
  const unsigned TB = baseKey;
  #pragma unroll
  for (int u = 0; u < NFULL; ++u) {
    unsigned k = fkey(sv[u]);
    if (k >= TB) {
      unsigned p = atomicAdd(&cnt, 1u);
      unsigned i = (unsigned)(tid + (u << 10));
      if (p < CAP) selPk[p] = ((ull)k << 32) | (unsigned)(~i);
    }
  }
  if (hastail) {
    unsigned k = fkey(stail);
    if (k >= TB) {
      unsigned p = atomicAdd(&cnt, 1u);
      unsigned i = (unsigned)(tid + NFULL * NT);
      if (p < CAP) selPk[p] = ((ull)k << 32) | (unsigned)(~i);
    }
  }
  __syncthreads();
  const unsigned realCnt = (cnt < CAP) ? cnt : CAP;
  for (unsigned i = realCnt + tid; i < CAP; i += NT) selPk[i] = 0ull;
  __syncthreads();

  // ---- hybrid bitonic sort 2048 descending ----
  {
    const int w = tid >> 6, L = tid & 63;
    const int ea = (w << 7) | (L << 1);       // element index of reg a; reg b = ea+1
    ull a = selPk[ea], bb = selPk[ea + 1];
    #pragma unroll
    for (unsigned k = 2; k <= 128; k <<= 1) {
      #pragma unroll
      for (unsigned j = k >> 1; j >= 2; j >>= 1) {
        bool up = ((ea & k) == 0);
        bool lower = ((ea & j) == 0);
        bool takeMax = (up == lower);
        ull oa = __shfl_xor(a, (int)(j >> 1));
        ull ob = __shfl_xor(bb, (int)(j >> 1));
        a  = takeMax ? (a  > oa ? a  : oa) : (a  < oa ? a  : oa);
        bb = takeMax ? (bb > ob ? bb : ob) : (bb < ob ? bb : ob);
      }
      bool up = ((ea & k) == 0);
      ull mx = a > bb ? a : bb, mn = a > bb ? bb : a;
      a = up ? mx : mn; bb = up ? mn : mx;
    }
    selPk[ea] = a; selPk[ea + 1] = bb;
    __syncthreads();
    for (unsigned k = 256; k <= 2048; k <<= 1) {
      for (unsigned j = k >> 1; j >= 128; j >>= 1) {
        unsigned p = (unsigned)tid;
        unsigned vi = ((p & ~(j - 1)) << 1) | (p & (j - 1));
        unsigned li = vi | j;
        ull av = selPk[vi], cv = selPk[li];
        bool doswap = ((vi & k) == 0) ? (av < cv) : (av > cv);
        if (doswap) { selPk[vi] = cv; selPk[li] = av; }
        __syncthreads();
      }
      a = selPk[ea]; bb = selPk[ea + 1];
      bool up = (((unsigned)(w << 7) & k) == 0);   // wave-uniform for k>=256
      #pragma unroll
      for (unsigned j = 64; j >= 2; j >>= 1) {
        bool lower = ((ea & j) == 0);
        bool takeMax = (up == lower);
        ull oa = __shfl_xor(a, (int)(j >> 1));
        ull ob = __shfl_xor(bb, (int)(j >> 1));
        a  = takeMax ? (a  > oa ? a  : oa) : (a  < oa ? a  : oa);
        bb = takeMax ? (bb > ob ? bb : ob) : (bb < ob ? bb : ob);
      }
      ull mx = a > bb ? a : bb, mn = a > bb ? bb : a;
      a = up ? mx : mn; bb = up ? mn : mx;
      selPk[ea] = a; selPk[ea + 1] = bb;
      __syncthreads();
    }
  }

  // ---- decode first 1000 into box arrays for NMS (float2 loads, L2-hot) ----
  if (tid < KSEL) {
    unsigned idx = ~(unsigned)selPk[tid];
    const float2* e2 = (const float2*)(xb + (size_t)idx * 6 + 2);
    float2 ra = e2[0], rb = e2[1];
    unsigned pp = (idx / 9u) % 60u;
    unsigned qq = idx / 540u;
    unsigned sr = idx % 9u;
    const float* ap = anch + (((pp * 40u + qq) * 9u + sr) * 4u);
    float ax = ap[0], ay = ap[1], aw = ap[2], ah = ap[3];
    float xc = ra.x * aw + ax;
    float yc = ra.y * ah + ay;
    float w = aw * expf(rb.x);
    float h = ah * expf(rb.y);
    float x1 = xc - 0.5f * w, x2 = xc + 0.5f * w;
    float y1 = yc - 0.5f * h, y2 = yc + 0.5f * h;
    bX1[tid] = x1; bY1[tid] = y1; bX2[tid] = x2; bY2[tid] = y2;
    bAr[tid] = (x2 - x1) * (y2 - y1);
  }
  __syncthreads();

  // ---- greedy NMS on wave 0, early exit at 18 kept ----
  if (tid < 64) {
    const int lane = tid;
    int nk = 0;
    float kx1 = 0.f, ky1 = 0.f, kx2 = 0.f, ky2 = 0.f;  // lane i holds kept box i
    int krank = -1;
    for (int base = 0; base < KSEL && nk < MAXB; base += 64) {
      int c = base + lane;
      bool alive = (c < KSEL);
      int cc = alive ? c : 0;
      float x1 = bX1[cc], y1 = bY1[cc], x2 = bX2[cc], y2 = bY2[cc], ar = bAr[cc];
      for (int i = 0; i < nk; ++i) {
        float px1 = __shfl(kx1, i), py1 = __shfl(ky1, i);
        float px2 = __shfl(kx2, i), py2 = __shfl(ky2, i);
        float iw = fmaxf(fminf(x2, px2) - fmaxf(x1, px1), 0.f);
        float ih = fmaxf(fminf(y2, py2) - fmaxf(y1, py1), 0.f);
        if (iw * ih / ar > 0.5f) alive = false;
      }
      unsigned long long m = __ballot(alive);
      while (m) {
        int i = __builtin_ctzll(m);      // lowest alive lane = best remaining score
        float px1 = __shfl(x1, i), py1 = __shfl(y1, i);
        float px2 = __shfl(x2, i), py2 = __shfl(y2, i);
        if (lane == nk) { kx1 = px1; ky1 = py1; kx2 = px2; ky2 = py2; krank = base + i; }
        ++nk;
        if (nk >= MAXB) break;
        if (alive && lane != i) {
          float iw = fmaxf(fminf(x2, px2) - fmaxf(x1, px1), 0.f);
          float ih = fmaxf(fminf(y2, py2) - fmaxf(y1, py1), 0.f);
          if (iw * ih / ar > 0.5f) alive = false;
        }
        if (lane == i) alive = false;
        m = __ballot(alive);
      }
    }
    if (lane == 0) numKept = nk;
    if (lane < nk) keptRank[lane] = krank;
  }
  __syncthreads();

  // ---- output: kept rows then pad rows cand[j - n]; score from key bits ----
  const int n = numKept;
  if (tid < MAXB) {
    int j = tid;
    int r = (j < n) ? keptRank[j] : (j - n);
    ull pk = selPk[r];
    unsigned idx = ~(unsigned)pk;
    float sc = unfkey((unsigned)(pk >> 32));
    const float2* e2 = (const float2*)(xb + (size_t)idx * 6 + 2);
    float2 ra = e2[0], rb = e2[1];
    unsigned pp = (idx / 9u) % 60u;
    unsigned qq = idx / 540u;
    unsigned sr = idx % 9u;
    const float* ap = anch + (((pp * 40u + qq) * 9u + sr) * 4u);
    float ax = ap[0], ay = ap[1], aw = ap[2], ah = ap[3];
    float xc = ra.x * aw + ax;
    float yc = ra.y * ah + ay;
    float w = aw * expf(rb.x);
    float h = ah * expf(rb.y);
    float* o = out + b * (MAXB * 5) + j * 5;
    o[0] = xc; o[1] = yc; o[2] = w; o[3] = h; o[4] = sc;
  }
}

extern "C" void kernel_launch(void* const* d_in, const int* in_sizes, int n_in,
                              void* d_out, int out_size, void* d_ws, size_t ws_size,
                              hipStream_t stream) {
  const float* x = (const float*)d_in[0];
  const float* anch = (const float*)d_in[1];
  float* out = (float*)d_out;
  const int B = in_sizes[0] / (NELEM * 6);
  rpn_kernel<<<dim3(B), dim3(NT), 0, stream>>>(x, anch, out);
}